// Round 6
// baseline (408.746 us; speedup 1.0000x reference)
//
#include <hip/hip_runtime.h>
#include <hip/hip_fp16.h>

// Problem constants
#define NN 100000
#define EE 500000
#define F_NODE 128
#define F_EDGE 32
#define HEADS 4
#define CC 64
#define HC 256
#define OUTD 32
#define NEG_SLOPE 0.2f
#define BN_SCALE 0.9999950000374997f   // 1/sqrt(1+1e-5)
#define NB_SCAN 391                    // ceil(NN/256)
#define MPAD 100096                    // NN padded to multiple of 128

using half8 = __attribute__((ext_vector_type(8))) _Float16;
using f32x4 = __attribute__((ext_vector_type(4))) float;

typedef const __attribute__((address_space(1))) void* gas_ptr;
typedef __attribute__((address_space(3))) void* las_ptr;

// ---------------------------------------------------------------------------
// Tiled MFMA GEMM: C[m][n] = sum_k A[m][k] * Wt[n][k]
//   A fp16 [M][K] row-major (M padded to >= grid*128 rows, garbage pad ok)
//   Wt fp16 [NOUT][K] row-major (weights pre-transposed)
//   C fp16 [M][NOUT] (padded; pad rows receive garbage, never read)
// Tile: BM=128 x BN=(128 or 64), BK=64. 4 waves in 2x2; each wave owns
// 64 x (BN/2) output = MIxNI 16x16 fragments.
// LDS: double-buffered A[128][64] + B[BN][64] fp16, linear dest via
// global_load_lds(16B), XOR-swizzled SOURCE (unit ^= row&7) and the same
// XOR applied on ds_read_b128 -> 2-way banks (free) instead of 16-way.
// One barrier per K-step, stage-ahead prefetch (m97 2-phase structure).
// MODE 1: + bias[col], ReLU.
// ATT 1 (requires BN=128): fused attention-score epilogue. Each wave covers
// 64 rows x 64 cols = one full head -> a_s[row][head] = sum_c acc*as_[col]
// computed from f32 accumulators, no atomics (each (row,head) owned by one
// wave). Replaces the att_score kernel and its full xh re-read per layer.
// ---------------------------------------------------------------------------
template<int K, int NOUT, int MODE, int ATT>
__global__ __launch_bounds__(256, 2) void mgemm2(const __half* __restrict__ A,
                                                 const __half* __restrict__ Wt,
                                                 const float* __restrict__ bias,
                                                 __half* __restrict__ C,
                                                 const float* __restrict__ as_,
                                                 const float* __restrict__ ad_,
                                                 float* __restrict__ a_s,
                                                 float* __restrict__ a_d) {
    constexpr int BM = 128;
    constexpr int BN = (NOUT >= 128) ? 128 : 64;
    constexpr int MI = 4;
    constexpr int NI = BN / 32;
    constexpr int KS = K / 64;
    constexpr int ABYTES = BM * 128;   // 128 rows x 64 halfs
    constexpr int BBYTES = BN * 128;
    __shared__ char smem[2 * (ABYTES + BBYTES)];

    const int tid  = threadIdx.x;
    const int wave = tid >> 6, lane = tid & 63;
    const int wr = wave >> 1, wc = wave & 1;
    const int lrow = lane & 15, kq = lane >> 4;
    const int m0 = blockIdx.x * BM;
    const int n0 = blockIdx.y * BN;
    const int srow = tid >> 3;         // 0..31 staging row within 32-row slab
    const int sunit = tid & 7;         // physical 16B unit within row
    const int wofs = (tid & 192) * 16; // wave-uniform LDS offset (w*1024)

    // stage one BK=64 tile of A and B into buffer `buf`
    auto stage = [&](int buf, int ks) {
        char* base = smem + buf * (ABYTES + BBYTES);
        const int kk = ks * 64;
#pragma unroll
        for (int it = 0; it < BM / 32; ++it) {
            const int r = srow + it * 32;
            const __half* src = A + (size_t)(m0 + r) * K + kk + ((sunit ^ (r & 7)) << 3);
            __builtin_amdgcn_global_load_lds((gas_ptr)src,
                (las_ptr)(base + it * 4096 + wofs), 16, 0, 0);
        }
#pragma unroll
        for (int it = 0; it < BN / 32; ++it) {
            const int r = srow + it * 32;
            const __half* src = Wt + (size_t)(n0 + r) * K + kk + ((sunit ^ (r & 7)) << 3);
            __builtin_amdgcn_global_load_lds((gas_ptr)src,
                (las_ptr)(base + ABYTES + it * 4096 + wofs), 16, 0, 0);
        }
    };

    f32x4 acc[MI][NI] = {};

    auto compute = [&](int buf) {
        const char* Ab = smem + buf * (ABYTES + BBYTES);
        const char* Bb = Ab + ABYTES;
#pragma unroll
        for (int k32 = 0; k32 < 2; ++k32) {
            const int ku = k32 * 4 + kq;       // logical 16B unit (0..7)
            half8 af[MI], bf[NI];
#pragma unroll
            for (int mi = 0; mi < MI; ++mi) {
                const int rr = wr * 64 + mi * 16 + lrow;
                af[mi] = *(const half8*)(Ab + rr * 128 + ((ku ^ (rr & 7)) << 4));
            }
#pragma unroll
            for (int ni = 0; ni < NI; ++ni) {
                const int rc = wc * (BN / 2) + ni * 16 + lrow;
                bf[ni] = *(const half8*)(Bb + rc * 128 + ((ku ^ (rc & 7)) << 4));
            }
#pragma unroll
            for (int mi = 0; mi < MI; ++mi)
#pragma unroll
                for (int ni = 0; ni < NI; ++ni)
                    acc[mi][ni] = __builtin_amdgcn_mfma_f32_16x16x32_f16(
                        af[mi], bf[ni], acc[mi][ni], 0, 0, 0);
        }
    };

    stage(0, 0);
    __syncthreads();                    // drain prologue stage
    int cur = 0;
#pragma unroll
    for (int ks = 0; ks < KS; ++ks) {
        if (ks + 1 < KS) stage(cur ^ 1, ks + 1);
        compute(cur);
        __syncthreads();                // drains next stage + guards re-stage
        cur ^= 1;
    }

    const int crow = kq * 4;
#pragma unroll
    for (int mi = 0; mi < MI; ++mi) {
#pragma unroll
        for (int ni = 0; ni < NI; ++ni) {
            const int col = n0 + wc * (BN / 2) + ni * 16 + lrow;
            float bcol = (MODE == 1) ? bias[col] : 0.f;
#pragma unroll
            for (int r = 0; r < 4; ++r) {
                float v = acc[mi][ni][r];
                if constexpr (MODE == 1) v = fmaxf(v + bcol, 0.f);
                const int row = m0 + wr * 64 + mi * 16 + crow + r;
                C[(size_t)row * NOUT + col] = __float2half(v);
            }
        }
    }

    if constexpr (ATT) {
        // wave covers one head's full 64 cols -> complete dot in-wave
        const int head = (n0 + wc * 64) >> 6;
        float wsv[NI], wdv[NI];
#pragma unroll
        for (int ni = 0; ni < NI; ++ni) {
            const int col = n0 + wc * (BN / 2) + ni * 16 + lrow;
            wsv[ni] = as_[col];
            wdv[ni] = ad_[col];
        }
#pragma unroll
        for (int mi = 0; mi < MI; ++mi) {
#pragma unroll
            for (int r = 0; r < 4; ++r) {
                float ss = 0.f, dd = 0.f;
#pragma unroll
                for (int ni = 0; ni < NI; ++ni) {
                    ss += acc[mi][ni][r] * wsv[ni];
                    dd += acc[mi][ni][r] * wdv[ni];
                }
#pragma unroll
                for (int off = 8; off >= 1; off >>= 1) {
                    ss += __shfl_xor(ss, off, 64);
                    dd += __shfl_xor(dd, off, 64);
                }
                if (lrow == 0) {
                    const int row = m0 + wr * 64 + mi * 16 + crow + r;
                    a_s[row * HEADS + head] = ss;
                    a_d[row * HEADS + head] = dd;
                }
            }
        }
    }
}

// ---------------------------------------------------------------------------
// Prep kernels: transpose-convert weights to fp16 NxK, cast x to fp16.
// ---------------------------------------------------------------------------
__global__ __launch_bounds__(256) void wt_conv(const float* __restrict__ W,
                                               __half* __restrict__ Wt,
                                               int K, int N) {
    int idx = blockIdx.x * 256 + threadIdx.x;   // over N*K, output-contiguous
    if (idx >= K * N) return;
    int n = idx / K, k = idx % K;
    Wt[idx] = __float2half(W[k * N + n]);
}

// Wt_final[n][k]: n<32 -> W1[k][n] (W1s), n>=32 -> W1[256+k][n-32] (W1d)
__global__ __launch_bounds__(256) void wt_final(const float* __restrict__ W1,
                                                __half* __restrict__ Wt) {
    int idx = blockIdx.x * 256 + threadIdx.x;   // over 64*256
    if (idx >= 64 * 256) return;
    int n = idx >> 8, k = idx & 255;
    float v = (n < 32) ? W1[k * 32 + n] : W1[(256 + k) * 32 + (n - 32)];
    Wt[idx] = __float2half(v);
}

__global__ __launch_bounds__(256) void cvt_x(const float* __restrict__ x,
                                             __half* __restrict__ x16) {
    int i = blockIdx.x * 256 + threadIdx.x;     // over NN*F_NODE/4
    float4 v = ((const float4*)x)[i];
    __half2* o = (__half2*)x16 + (size_t)i * 2;
    o[0] = __floats2half2_rn(v.x, v.y);
    o[1] = __floats2half2_rn(v.z, v.w);
}

// ---------------------------------------------------------------------------
// CSR build: deg-count, two-level exclusive scan, scatter.
// ---------------------------------------------------------------------------
__global__ __launch_bounds__(256) void csr_count(const int* __restrict__ dst,
                                                 int* __restrict__ deg,
                                                 int* __restrict__ pos) {
    int e = blockIdx.x * 256 + threadIdx.x;
    if (e >= EE) return;
    pos[e] = atomicAdd(deg + dst[e], 1);
}

__device__ __forceinline__ int wave_incl_scan(int v, int lane) {
#pragma unroll
    for (int off = 1; off < 64; off <<= 1) {
        int t = __shfl_up(v, off, 64);
        if (lane >= off) v += t;
    }
    return v;
}

__global__ __launch_bounds__(256) void scan1(const int* __restrict__ deg,
                                             int* __restrict__ rowptr,
                                             int* __restrict__ bsum) {
    int tid = threadIdx.x, n = blockIdx.x * 256 + tid;
    int lane = tid & 63, wave = tid >> 6;
    int d = (n < NN) ? deg[n] : 0;
    int v = wave_incl_scan(d, lane);
    __shared__ int ws[4];
    if (lane == 63) ws[wave] = v;
    __syncthreads();
    int woff = 0;
    for (int w = 0; w < wave; ++w) woff += ws[w];
    int incl = v + woff;
    if (n < NN) rowptr[n] = incl - d;
    if (tid == 255) bsum[blockIdx.x] = incl;
}

__global__ __launch_bounds__(512) void scan2(const int* __restrict__ bsum,
                                             int* __restrict__ boff) {
    int t = threadIdx.x;
    int lane = t & 63, wave = t >> 6;
    int d = (t < NB_SCAN) ? bsum[t] : 0;
    int v = wave_incl_scan(d, lane);
    __shared__ int ws[8];
    if (lane == 63) ws[wave] = v;
    __syncthreads();
    int woff = 0;
    for (int w = 0; w < wave; ++w) woff += ws[w];
    if (t < NB_SCAN) boff[t] = v + woff - d;
}

__global__ __launch_bounds__(256) void scan3(int* __restrict__ rowptr,
                                             const int* __restrict__ boff) {
    int n = blockIdx.x * 256 + threadIdx.x;
    if (n == 0) rowptr[NN] = EE;
    if (n < NN) rowptr[n] += boff[blockIdx.x];
}

__global__ __launch_bounds__(256) void csr_scatter(const int* __restrict__ src,
                                                   const int* __restrict__ dst,
                                                   const int* __restrict__ rowptr,
                                                   const int* __restrict__ pos,
                                                   int* __restrict__ srcs) {
    int e = blockIdx.x * 256 + threadIdx.x;
    if (e >= EE) return;
    srcs[rowptr[dst[e]] + pos[e]] = src[e];
}

// ---------------------------------------------------------------------------
// Gather-aggregate with FUSED edge scoring + BN/ReLU/residual.
// One wave per dst node. Wave-cooperative scoring: per 8-edge iteration,
// lane l (slot=l&7, head=(l>>3)&3; lanes 32-63 mirror) computes ONE
// (edge,head) score = exp(lrelu(a_s[src]+a_d[n])) -- 1 srcs load + 1 a_s
// load + 1 exp instead of 4 each per lane (old version recomputed scores
// redundantly in every lane: 8x VMEM + 8x exp). Gather lanes pull (s,e)
// via __shfl (ds_bpermute, rides idle LDS pipe). Gather phase unchanged:
// half-wave owns edge-slot parity, 16B half8 loads, 8 rows in flight.
// ---------------------------------------------------------------------------
__global__ __launch_bounds__(256) void gather_agg(const int* __restrict__ rowptr,
                                                  const int* __restrict__ srcs,
                                                  const float* __restrict__ a_s,
                                                  const float* __restrict__ a_d,
                                                  const __half* __restrict__ xh,
                                                  const float* __restrict__ bg,
                                                  const float* __restrict__ g,
                                                  const float* __restrict__ be,
                                                  __half* __restrict__ h,
                                                  int residual) {
    const int n = blockIdx.x * 4 + (threadIdx.x >> 6);
    const int lane = threadIdx.x & 63;
    // grid is exactly NN/4 nodes -> no bounds guard needed (NN % 4 == 0)
    const int slot  = lane & 7;          // score phase: my edge slot
    const int shead = (lane >> 3) & 3;   // score phase: my head
    const int hl = lane >> 5;            // gather phase: edge-slot parity
    const int l5 = lane & 31;
    const int hd = l5 >> 3;              // gather phase: head of my 8 cols
    const int c0 = l5 * 8;               // col base (16B aligned)

    const int start = rowptr[n], end = rowptr[n + 1];
    const float adv = a_d[n * HEADS + shead];

    float acc[8] = {};
    float den = 0.f;

    const int sl_base = (hd << 3) | hl;  // source lane for (my hd, slot hl+2g)

    for (int i = start; i < end; i += 8) {
        // ---- score phase: one (edge,head) per lane ----
        const int jj = i + slot;
        const bool ok = jj < end;
        const int j = ok ? jj : (end - 1);
        const int sme = srcs[j];
        float v = a_s[sme * HEADS + shead] + adv;
        v = fmaxf(v, v * NEG_SLOPE);
        const float eme = ok ? __expf(v) : 0.f;

        // ---- broadcast (s, e) to gather lanes via bpermute ----
        const int   s0 = __shfl(sme, sl_base,     64);
        const float e0 = __shfl(eme, sl_base,     64);
        const int   s1 = __shfl(sme, sl_base + 2, 64);
        const float e1 = __shfl(eme, sl_base + 2, 64);
        const int   s2 = __shfl(sme, sl_base + 4, 64);
        const float e2 = __shfl(eme, sl_base + 4, 64);
        const int   s3 = __shfl(sme, sl_base + 6, 64);
        const float e3 = __shfl(eme, sl_base + 6, 64);

        // ---- gather phase: 4 x 16B row-fragments in flight ----
        half8 r0 = *(const half8*)(xh + (size_t)s0 * HC + c0);
        half8 r1 = *(const half8*)(xh + (size_t)s1 * HC + c0);
        half8 r2 = *(const half8*)(xh + (size_t)s2 * HC + c0);
        half8 r3 = *(const half8*)(xh + (size_t)s3 * HC + c0);

#pragma unroll
        for (int k = 0; k < 8; ++k)
            acc[k] += e0 * (float)r0[k] + e1 * (float)r1[k]
                    + e2 * (float)r2[k] + e3 * (float)r3[k];
        den += e0 + e1 + e2 + e3;
    }

    // combine the two half-waves (same node, disjoint edge subsets)
    den += __shfl_xor(den, 32, 64);
#pragma unroll
    for (int k = 0; k < 8; ++k) acc[k] += __shfl_xor(acc[k], 32, 64);

    if (hl != 0) return;               // half 0 holds full sums; writes row
    const float inv = 1.f / (den + 1e-16f);

    float bgv[8], gv[8], bev[8];
    *(float4*)(bgv)     = *(const float4*)(bg + c0);
    *(float4*)(bgv + 4) = *(const float4*)(bg + c0 + 4);
    *(float4*)(gv)      = *(const float4*)(g + c0);
    *(float4*)(gv + 4)  = *(const float4*)(g + c0 + 4);
    *(float4*)(bev)     = *(const float4*)(be + c0);
    *(float4*)(bev + 4) = *(const float4*)(be + c0 + 4);

    half8* hp = (half8*)(h + (size_t)n * HC + c0);
    float r[8];
#pragma unroll
    for (int k = 0; k < 8; ++k)
        r[k] = fmaxf((acc[k] * inv + bgv[k]) * (gv[k] * BN_SCALE) + bev[k], 0.f);
    if (residual) {
        half8 old = *hp;
#pragma unroll
        for (int k = 0; k < 8; ++k) r[k] += (float)old[k];
    }
    half8 o;
#pragma unroll
    for (int k = 0; k < 8; ++k) o[k] = (_Float16)r[k];
    __builtin_nontemporal_store(o, hp);   // don't let h-stream evict xh
}

// ---------------------------------------------------------------------------
// Final fused edge MLP:
// Phase 1: per block, 64 edges; MFMA computes z_pre = ea@W1e + b1 into LDS.
// Phase 2: 4 threads/edge gather hs[src], hd[dst], ReLU, dot(W2), reduce.
// ---------------------------------------------------------------------------
__global__ __launch_bounds__(256) void edge_final(const float* __restrict__ ea,
                                                  const __half* __restrict__ w1et,
                                                  const float* __restrict__ b1,
                                                  const int* __restrict__ src,
                                                  const int* __restrict__ dst,
                                                  const __half* __restrict__ hshd,
                                                  const float* __restrict__ W2,
                                                  const float* __restrict__ b2,
                                                  float* __restrict__ out) {
    __shared__ float zl[64][36];   // stride 36: 16B-aligned rows, <=2-way banks
    const int wave = threadIdx.x >> 6, lane = threadIdx.x & 63;
    const int e0 = blockIdx.x * 64;
    const int lrow = lane & 15, kofs = (lane >> 4) * 8;

    // ---- Phase 1: MFMA z = ea @ W1e (K=32), 16 edges per wave ----
    int er = e0 + wave * 16 + lrow;
    if (er >= EE) er = EE - 1;
    const float* ap = ea + (size_t)er * F_EDGE + kofs;
    float4 f0 = *(const float4*)ap;
    float4 f1 = *(const float4*)(ap + 4);
    half8 a;
    a[0] = (_Float16)f0.x; a[1] = (_Float16)f0.y;
    a[2] = (_Float16)f0.z; a[3] = (_Float16)f0.w;
    a[4] = (_Float16)f1.x; a[5] = (_Float16)f1.y;
    a[6] = (_Float16)f1.z; a[7] = (_Float16)f1.w;

    half8 b0 = *(const half8*)(w1et + (size_t)lrow * 32 + kofs);
    half8 b1v = *(const half8*)(w1et + (size_t)(16 + lrow) * 32 + kofs);
    f32x4 acc0 = {}, acc1 = {};
    acc0 = __builtin_amdgcn_mfma_f32_16x16x32_f16(a, b0,  acc0, 0, 0, 0);
    acc1 = __builtin_amdgcn_mfma_f32_16x16x32_f16(a, b1v, acc1, 0, 0, 0);

    const int crow = (lane >> 4) * 4;
    const float bc0 = b1[lrow], bc1 = b1[16 + lrow];
#pragma unroll
    for (int r = 0; r < 4; ++r) {
        zl[wave * 16 + crow + r][lrow]      = acc0[r] + bc0;
        zl[wave * 16 + crow + r][16 + lrow] = acc1[r] + bc1;
    }
    __syncthreads();

    // ---- Phase 2: gather + ReLU + dot(W2) ----
    const int el = threadIdx.x >> 2, j0 = (threadIdx.x & 3) * 8;
    const int e = e0 + el;
    const bool ok = e < EE;
    const int s = ok ? src[e] : 0;
    const int d = ok ? dst[e] : 0;

    half8 hs = *(const half8*)(hshd + (size_t)s * 64 + j0);
    half8 hdv = *(const half8*)(hshd + (size_t)d * 64 + 32 + j0);
    float w2v[8];
    *(float4*)(w2v)     = *(const float4*)(W2 + j0);
    *(float4*)(w2v + 4) = *(const float4*)(W2 + j0 + 4);
    float4 z0 = *(const float4*)&zl[el][j0];
    float4 z1 = *(const float4*)&zl[el][j0 + 4];

    float acc = 0.f;
    const float* zp0 = &z0.x;
    const float* zp1 = &z1.x;
#pragma unroll
    for (int i = 0; i < 4; ++i) {
        float z = zp0[i] + (float)hs[i] + (float)hdv[i];
        acc += fmaxf(z, 0.f) * w2v[i];
    }
#pragma unroll
    for (int i = 0; i < 4; ++i) {
        float z = zp1[i] + (float)hs[4 + i] + (float)hdv[4 + i];
        acc += fmaxf(z, 0.f) * w2v[4 + i];
    }
    acc += __shfl_xor(acc, 1, 64);
    acc += __shfl_xor(acc, 2, 64);
    if (ok && (threadIdx.x & 3) == 0) out[e] = acc + b2[0];
}

// ---------------------------------------------------------------------------
extern "C" void kernel_launch(void* const* d_in, const int* in_sizes, int n_in,
                              void* d_out, int out_size, void* d_ws, size_t ws_size,
                              hipStream_t stream) {
    const float* x  = (const float*)d_in[0];
    const int*   ei = (const int*)d_in[1];
    const float* ea = (const float*)d_in[2];
    const float* Wp = (const float*)d_in[3];
    const float* bp = (const float*)d_in[4];
    const float* W1 = (const float*)d_in[23];
    const float* b1 = (const float*)d_in[24];
    const float* W2 = (const float*)d_in[25];
    const float* b2 = (const float*)d_in[26];
    const int* src = ei;
    const int* dst = ei + EE;

    // Workspace layout (float offsets). All matrix buffers padded to MPAD
    // rows so the 782-block (128-row) GEMM grid needs no bounds checks.
    // a_s/a_d sized MPAD*HEADS (pad rows written by the ATT epilogue).
    float* ws = (float*)d_ws;
    __half* h      = (__half*)(ws);               // MPAD*256 halfs
    __half* xh     = (__half*)(ws + 12820000);    // MPAD*256 halfs
    __half* x16    = (__half*)(ws + 25640000);    // MPAD*128 halfs
    __half* h0     = (__half*)(ws + 32050000);    // MPAD*64 halfs
    __half* hshd   = (__half*)(ws + 35260000);    // MPAD*64 halfs
    float*  a_s    = ws + 38470000;               // MPAD*4 (410000 slot)
    float*  a_d    = ws + 38880000;               // MPAD*4
    int*    rowptr = (int*)(ws + 41270000);       // NN+1
    int*    deg    = (int*)(ws + 41380000);       // NN
    int*    pos    = (int*)(ws + 41480000);       // EE
    int*    srcs   = (int*)(ws + 42490000);       // EE
    int*    bsum   = (int*)(ws + 42990000);       // NB_SCAN
    int*    boff   = (int*)(ws + 42991000);       // NB_SCAN
    __half* wpt    = (__half*)(ws + 42992000);    // 64x128 (reused as w1et)
    __half* wgt    = (__half*)(ws + 43000000);    // 256x256
    __half* w1t    = (__half*)(ws + 43020000);    // 64x256
    float*  out    = (float*)d_out;

    const int MB = MPAD / 128;   // 782 row-blocks

    // ---- CSR build (once) ----
    hipMemsetAsync(deg, 0, (size_t)NN * sizeof(int), stream);
    csr_count<<<(EE + 255) / 256, 256, 0, stream>>>(dst, deg, pos);
    scan1<<<NB_SCAN, 256, 0, stream>>>(deg, rowptr, bsum);
    scan2<<<1, 512, 0, stream>>>(bsum, boff);
    scan3<<<NB_SCAN, 256, 0, stream>>>(rowptr, boff);
    csr_scatter<<<(EE + 255) / 256, 256, 0, stream>>>(src, dst, rowptr, pos, srcs);

    // ---- prep: x->fp16, Wp^T ----
    cvt_x<<<NN * F_NODE / 4 / 256, 256, 0, stream>>>(x, x16);
    wt_conv<<<(F_NODE * 64 + 255) / 256, 256, 0, stream>>>(Wp, wpt, F_NODE, 64);

    // h0 = relu(x @ Wp + bp)
    mgemm2<F_NODE, 64, 1, 0><<<dim3(MB, 1), 256, 0, stream>>>(
        x16, wpt, bp, h0, nullptr, nullptr, nullptr, nullptr);

    for (int l = 0; l < 3; ++l) {
        const float* Wg  = (const float*)d_in[5 + 6 * l];
        const float* as_ = (const float*)d_in[6 + 6 * l];
        const float* ad_ = (const float*)d_in[7 + 6 * l];
        const float* bg  = (const float*)d_in[8 + 6 * l];
        const float* g   = (const float*)d_in[9 + 6 * l];
        const float* be  = (const float*)d_in[10 + 6 * l];

        if (l == 0) {
            wt_conv<<<(CC * HC + 255) / 256, 256, 0, stream>>>(Wg, wgt, CC, HC);
            mgemm2<CC, HC, 0, 1><<<dim3(MB, 2), 256, 0, stream>>>(
                h0, wgt, nullptr, xh, as_, ad_, a_s, a_d);
        } else {
            wt_conv<<<(HC * HC + 255) / 256, 256, 0, stream>>>(Wg, wgt, HC, HC);
            mgemm2<HC, HC, 0, 1><<<dim3(MB, 2), 256, 0, stream>>>(
                h, wgt, nullptr, xh, as_, ad_, a_s, a_d);
        }

        gather_agg<<<NN / 4, 256, 0, stream>>>(rowptr, srcs, a_s, a_d, xh,
                                               bg, g, be, h, l > 0 ? 1 : 0);
    }

    // hs|hd = h @ [W1s | W1d]
    wt_final<<<(64 * 256 + 255) / 256, 256, 0, stream>>>(W1, w1t);
    mgemm2<HC, 64, 0, 0><<<dim3(MB, 1), 256, 0, stream>>>(
        h, w1t, nullptr, hshd, nullptr, nullptr, nullptr, nullptr);

    // W1e^T -> fp16 (reuse wpt; first mgemm2 that used it is long done)
    wt_conv<<<(32 * 32 + 255) / 256, 256, 0, stream>>>(W1 + 2 * HC * OUTD, wpt, 32, 32);
    edge_final<<<(EE + 63) / 64, 256, 0, stream>>>(ea, wpt, b1, src, dst, hshd, W2, b2, out);
}

// Round 7
// 374.269 us; speedup vs baseline: 1.0921x; 1.0921x over previous
//
#include <hip/hip_runtime.h>
#include <hip/hip_fp16.h>

// Problem constants
#define NN 100000
#define EE 500000
#define F_NODE 128
#define F_EDGE 32
#define HEADS 4
#define CC 64
#define HC 256
#define OUTD 32
#define NEG_SLOPE 0.2f
#define BN_SCALE 0.9999950000374997f   // 1/sqrt(1+1e-5)
#define NB_SCAN 391                    // ceil(NN/256)
#define MPAD 100096                    // NN padded to multiple of 128

using half8 = __attribute__((ext_vector_type(8))) _Float16;
using f32x4 = __attribute__((ext_vector_type(4))) float;

typedef const __attribute__((address_space(1))) void* gas_ptr;
typedef __attribute__((address_space(3))) void* las_ptr;

// ---------------------------------------------------------------------------
// Tiled MFMA GEMM: C[m][n] = sum_k A[m][k] * Wt[n][k]
//   A fp16 [M][K] row-major (M padded; garbage pad rows ok)  -- or, with
//   AF32=1, A32 fp32 [NN][K] (exact-size input; rows clamped to NN-1 and
//   converted fp32->fp16 during reg-staged LDS fill, deleting the separate
//   cvt_x pass).
//   Wt fp16 [NOUT][K] row-major (weights pre-transposed)
//   C fp16 [M][NOUT] (padded; pad rows receive garbage, never read)
// Tile: BM=128 x BN=(128 or 64), BK=64. 4 waves in 2x2.
// LDS: double-buffered, XOR-swizzled (source-side for global_load_lds,
// write-side for the AF32 reg-staged path; read applies the same XOR).
// MODE 1: + bias[col], ReLU.
// ATT 1 (requires BN=128): fused attention-score epilogue (a_s/a_d from
// f32 accumulators; each (row,head) owned by exactly one wave).
// ---------------------------------------------------------------------------
template<int K, int NOUT, int MODE, int ATT, int AF32>
__global__ __launch_bounds__(256, 2) void mgemm2(const __half* __restrict__ A,
                                                 const __half* __restrict__ Wt,
                                                 const float* __restrict__ bias,
                                                 __half* __restrict__ C,
                                                 const float* __restrict__ as_,
                                                 const float* __restrict__ ad_,
                                                 float* __restrict__ a_s,
                                                 float* __restrict__ a_d,
                                                 const float* __restrict__ A32) {
    constexpr int BM = 128;
    constexpr int BN = (NOUT >= 128) ? 128 : 64;
    constexpr int MI = 4;
    constexpr int NI = BN / 32;
    constexpr int KS = K / 64;
    constexpr int ABYTES = BM * 128;   // 128 rows x 64 halfs
    constexpr int BBYTES = BN * 128;
    __shared__ char smem[2 * (ABYTES + BBYTES)];

    const int tid  = threadIdx.x;
    const int wave = tid >> 6, lane = tid & 63;
    const int wr = wave >> 1, wc = wave & 1;
    const int lrow = lane & 15, kq = lane >> 4;
    const int m0 = blockIdx.x * BM;
    const int n0 = blockIdx.y * BN;
    const int srow = tid >> 3;         // 0..31 staging row within 32-row slab
    const int sunit = tid & 7;         // 16B unit within row
    const int wofs = (tid & 192) * 16; // wave-uniform LDS offset (w*1024)

    auto stageA16 = [&](int buf, int ks) {
        char* base = smem + buf * (ABYTES + BBYTES);
        const int kk = ks * 64;
#pragma unroll
        for (int it = 0; it < 4; ++it) {
            const int r = srow + it * 32;
            const __half* src = A + (size_t)(m0 + r) * K + kk + ((sunit ^ (r & 7)) << 3);
            __builtin_amdgcn_global_load_lds((gas_ptr)src,
                (las_ptr)(base + it * 4096 + wofs), 16, 0, 0);
        }
    };
    auto stageB = [&](int buf, int ks) {
        char* base = smem + buf * (ABYTES + BBYTES);
        const int kk = ks * 64;
#pragma unroll
        for (int it = 0; it < BN / 32; ++it) {
            const int r = srow + it * 32;
            const __half* src = Wt + (size_t)(n0 + r) * K + kk + ((sunit ^ (r & 7)) << 3);
            __builtin_amdgcn_global_load_lds((gas_ptr)src,
                (las_ptr)(base + ABYTES + it * 4096 + wofs), 16, 0, 0);
        }
    };

    float4 ar[4][2];                   // AF32 reg-staging (static-indexed)
    auto loadA32 = [&](int ks) {
        const int kk = ks * 64;
#pragma unroll
        for (int it = 0; it < 4; ++it) {
            int rg = m0 + srow + it * 32;
            rg = (rg < NN) ? rg : NN - 1;   // input is exact-size: clamp
            const float* sp = A32 + (size_t)rg * K + kk + sunit * 8;
            ar[it][0] = *(const float4*)sp;
            ar[it][1] = *(const float4*)(sp + 4);
        }
    };
    auto writeA32 = [&](int buf) {
        char* base = smem + buf * (ABYTES + BBYTES);
#pragma unroll
        for (int it = 0; it < 4; ++it) {
            const int r = srow + it * 32;
            half8 hv;
            hv[0] = (_Float16)ar[it][0].x; hv[1] = (_Float16)ar[it][0].y;
            hv[2] = (_Float16)ar[it][0].z; hv[3] = (_Float16)ar[it][0].w;
            hv[4] = (_Float16)ar[it][1].x; hv[5] = (_Float16)ar[it][1].y;
            hv[6] = (_Float16)ar[it][1].z; hv[7] = (_Float16)ar[it][1].w;
            *(half8*)(base + r * 128 + ((sunit ^ (r & 7)) << 4)) = hv;
        }
    };

    f32x4 acc[MI][NI] = {};

    auto compute = [&](int buf) {
        const char* Ab = smem + buf * (ABYTES + BBYTES);
        const char* Bb = Ab + ABYTES;
#pragma unroll
        for (int k32 = 0; k32 < 2; ++k32) {
            const int ku = k32 * 4 + kq;       // logical 16B unit (0..7)
            half8 af[MI], bf[NI];
#pragma unroll
            for (int mi = 0; mi < MI; ++mi) {
                const int rr = wr * 64 + mi * 16 + lrow;
                af[mi] = *(const half8*)(Ab + rr * 128 + ((ku ^ (rr & 7)) << 4));
            }
#pragma unroll
            for (int ni = 0; ni < NI; ++ni) {
                const int rc = wc * (BN / 2) + ni * 16 + lrow;
                bf[ni] = *(const half8*)(Bb + rc * 128 + ((ku ^ (rc & 7)) << 4));
            }
#pragma unroll
            for (int mi = 0; mi < MI; ++mi)
#pragma unroll
                for (int ni = 0; ni < NI; ++ni)
                    acc[mi][ni] = __builtin_amdgcn_mfma_f32_16x16x32_f16(
                        af[mi], bf[ni], acc[mi][ni], 0, 0, 0);
        }
    };

    // prologue stage
    if constexpr (AF32) { loadA32(0); stageB(0, 0); writeA32(0); }
    else                { stageA16(0, 0); stageB(0, 0); }
    __syncthreads();
    int cur = 0;
#pragma unroll
    for (int ks = 0; ks < KS; ++ks) {
        if (ks + 1 < KS) {
            if constexpr (AF32) { loadA32(ks + 1); stageB(cur ^ 1, ks + 1); }
            else                { stageA16(cur ^ 1, ks + 1); stageB(cur ^ 1, ks + 1); }
        }
        compute(cur);
        if constexpr (AF32) { if (ks + 1 < KS) writeA32(cur ^ 1); }
        __syncthreads();
        cur ^= 1;
    }

    const int crow = kq * 4;
#pragma unroll
    for (int mi = 0; mi < MI; ++mi) {
#pragma unroll
        for (int ni = 0; ni < NI; ++ni) {
            const int col = n0 + wc * (BN / 2) + ni * 16 + lrow;
            float bcol = (MODE == 1) ? bias[col] : 0.f;
#pragma unroll
            for (int r = 0; r < 4; ++r) {
                float v = acc[mi][ni][r];
                if constexpr (MODE == 1) v = fmaxf(v + bcol, 0.f);
                const int row = m0 + wr * 64 + mi * 16 + crow + r;
                C[(size_t)row * NOUT + col] = __float2half(v);
            }
        }
    }

    if constexpr (ATT) {
        // wave covers one head's full 64 cols -> complete dot in-wave
        const int head = (n0 + wc * 64) >> 6;
        float wsv[NI], wdv[NI];
#pragma unroll
        for (int ni = 0; ni < NI; ++ni) {
            const int col = n0 + wc * (BN / 2) + ni * 16 + lrow;
            wsv[ni] = as_[col];
            wdv[ni] = ad_[col];
        }
#pragma unroll
        for (int mi = 0; mi < MI; ++mi) {
#pragma unroll
            for (int r = 0; r < 4; ++r) {
                float ss = 0.f, dd = 0.f;
#pragma unroll
                for (int ni = 0; ni < NI; ++ni) {
                    ss += acc[mi][ni][r] * wsv[ni];
                    dd += acc[mi][ni][r] * wdv[ni];
                }
#pragma unroll
                for (int off = 8; off >= 1; off >>= 1) {
                    ss += __shfl_xor(ss, off, 64);
                    dd += __shfl_xor(dd, off, 64);
                }
                if (lrow == 0) {
                    const int row = m0 + wr * 64 + mi * 16 + crow + r;
                    a_s[row * HEADS + head] = ss;
                    a_d[row * HEADS + head] = dd;
                }
            }
        }
    }
}

// ---------------------------------------------------------------------------
// ONE prep kernel for all weight transposes (replaces 7 wt_conv/wt_final
// launches -> kills ~6 launch gaps and the per-layer wt_conv->GEMM serial
// dependency). Segments are contiguous index ranges -> wave-uniform branch.
// ---------------------------------------------------------------------------
#define PREP_TOTAL (8192 + 16384 + 65536 + 65536 + 16384 + 1024)
__global__ __launch_bounds__(256) void prep_all(const float* __restrict__ Wp,
                                                const float* __restrict__ Wg0,
                                                const float* __restrict__ Wg1,
                                                const float* __restrict__ Wg2,
                                                const float* __restrict__ W1,
                                                __half* __restrict__ wpt,
                                                __half* __restrict__ wg0t,
                                                __half* __restrict__ wg1t,
                                                __half* __restrict__ wg2t,
                                                __half* __restrict__ w1t,
                                                __half* __restrict__ w1et) {
    int idx = blockIdx.x * 256 + threadIdx.x;
    if (idx < 8192) {                                   // Wp^T: 64 x 128
        int n = idx >> 7, k = idx & 127;
        wpt[idx] = __float2half(Wp[k * 64 + n]);
    } else if (idx < 24576) {                           // Wg0^T: 256 x 64
        int i = idx - 8192;
        int n = i >> 6, k = i & 63;
        wg0t[i] = __float2half(Wg0[k * 256 + n]);
    } else if (idx < 90112) {                           // Wg1^T: 256 x 256
        int i = idx - 24576;
        int n = i >> 8, k = i & 255;
        wg1t[i] = __float2half(Wg1[k * 256 + n]);
    } else if (idx < 155648) {                          // Wg2^T: 256 x 256
        int i = idx - 90112;
        int n = i >> 8, k = i & 255;
        wg2t[i] = __float2half(Wg2[k * 256 + n]);
    } else if (idx < 172032) {                          // [W1s|W1d]^T: 64 x 256
        int i = idx - 155648;
        int n = i >> 8, k = i & 255;
        float v = (n < 32) ? W1[k * 32 + n] : W1[(256 + k) * 32 + (n - 32)];
        w1t[i] = __float2half(v);
    } else if (idx < PREP_TOTAL) {                      // W1e^T: 32 x 32
        int i = idx - 172032;
        int n = i >> 5, k = i & 31;
        w1et[i] = __float2half(W1[2 * HC * OUTD + k * 32 + n]);
    }
}

// ---------------------------------------------------------------------------
// CSR build: deg-count, two-level exclusive scan, scatter.
// ---------------------------------------------------------------------------
__global__ __launch_bounds__(256) void csr_count(const int* __restrict__ dst,
                                                 int* __restrict__ deg,
                                                 int* __restrict__ pos) {
    int e = blockIdx.x * 256 + threadIdx.x;
    if (e >= EE) return;
    pos[e] = atomicAdd(deg + dst[e], 1);
}

__device__ __forceinline__ int wave_incl_scan(int v, int lane) {
#pragma unroll
    for (int off = 1; off < 64; off <<= 1) {
        int t = __shfl_up(v, off, 64);
        if (lane >= off) v += t;
    }
    return v;
}

__global__ __launch_bounds__(256) void scan1(const int* __restrict__ deg,
                                             int* __restrict__ rowptr,
                                             int* __restrict__ bsum) {
    int tid = threadIdx.x, n = blockIdx.x * 256 + tid;
    int lane = tid & 63, wave = tid >> 6;
    int d = (n < NN) ? deg[n] : 0;
    int v = wave_incl_scan(d, lane);
    __shared__ int ws[4];
    if (lane == 63) ws[wave] = v;
    __syncthreads();
    int woff = 0;
    for (int w = 0; w < wave; ++w) woff += ws[w];
    int incl = v + woff;
    if (n < NN) rowptr[n] = incl - d;
    if (tid == 255) bsum[blockIdx.x] = incl;
}

__global__ __launch_bounds__(512) void scan2(const int* __restrict__ bsum,
                                             int* __restrict__ boff) {
    int t = threadIdx.x;
    int lane = t & 63, wave = t >> 6;
    int d = (t < NB_SCAN) ? bsum[t] : 0;
    int v = wave_incl_scan(d, lane);
    __shared__ int ws[8];
    if (lane == 63) ws[wave] = v;
    __syncthreads();
    int woff = 0;
    for (int w = 0; w < wave; ++w) woff += ws[w];
    if (t < NB_SCAN) boff[t] = v + woff - d;
}

__global__ __launch_bounds__(256) void scan3(int* __restrict__ rowptr,
                                             const int* __restrict__ boff) {
    int n = blockIdx.x * 256 + threadIdx.x;
    if (n == 0) rowptr[NN] = EE;
    if (n < NN) rowptr[n] += boff[blockIdx.x];
}

__global__ __launch_bounds__(256) void csr_scatter(const int* __restrict__ src,
                                                   const int* __restrict__ dst,
                                                   const int* __restrict__ rowptr,
                                                   const int* __restrict__ pos,
                                                   int* __restrict__ srcs) {
    int e = blockIdx.x * 256 + threadIdx.x;
    if (e >= EE) return;
    srcs[rowptr[dst[e]] + pos[e]] = src[e];
}

// ---------------------------------------------------------------------------
// Gather-aggregate with FUSED edge scoring + BN/ReLU/residual.  [R4 body --
// the R5 wave-cooperative scoring regressed: its __shfl broadcast made the
// xh gathers depend on score completion, serializing the load chain. Here
// scores are computed redundantly per lane but INDEPENDENTLY, so the
// srcs->xh load chain issues immediately and overlaps the exp chain.]
// One wave per dst node; each HALF-wave owns one edge-slot parity with 16B
// half8 loads; x4 unroll per half = 8 rows in flight per wave.
// ---------------------------------------------------------------------------
__global__ __launch_bounds__(256) void gather_agg(const int* __restrict__ rowptr,
                                                  const int* __restrict__ srcs,
                                                  const float* __restrict__ a_s,
                                                  const float* __restrict__ a_d,
                                                  const __half* __restrict__ xh,
                                                  const float* __restrict__ bg,
                                                  const float* __restrict__ g,
                                                  const float* __restrict__ be,
                                                  __half* __restrict__ h,
                                                  int residual) {
    const int n = blockIdx.x * 4 + (threadIdx.x >> 6);   // grid = NN/4 exact
    const int lane = threadIdx.x & 63;
    const int hl = lane >> 5;          // half-wave: edge-slot parity
    const int l5 = lane & 31;
    const int hd = l5 >> 3;            // head of my 8 cols
    const int c0 = l5 * 8;             // col base (16B aligned)

    const int start = rowptr[n], end = rowptr[n + 1];
    const float adv = a_d[n * HEADS + hd];

    float acc[8] = {};
    float den = 0.f;

    for (int i = start + hl; i < end; i += 8) {
        // 4 slots per half: i, i+2, i+4, i+6 (clamped; zero weight past end)
        int  j1 = (i + 2 < end) ? i + 2 : i;
        int  j2 = (i + 4 < end) ? i + 4 : i;
        int  j3 = (i + 6 < end) ? i + 6 : i;
        const int s0 = srcs[i], s1 = srcs[j1], s2 = srcs[j2], s3 = srcs[j3];

        float v0 = a_s[s0 * HEADS + hd] + adv;
        float v1 = a_s[s1 * HEADS + hd] + adv;
        float v2 = a_s[s2 * HEADS + hd] + adv;
        float v3 = a_s[s3 * HEADS + hd] + adv;
        v0 = fmaxf(v0, v0 * NEG_SLOPE);
        v1 = fmaxf(v1, v1 * NEG_SLOPE);
        v2 = fmaxf(v2, v2 * NEG_SLOPE);
        v3 = fmaxf(v3, v3 * NEG_SLOPE);
        float e0 = __expf(v0);
        float e1 = (i + 2 < end) ? __expf(v1) : 0.f;
        float e2 = (i + 4 < end) ? __expf(v2) : 0.f;
        float e3 = (i + 6 < end) ? __expf(v3) : 0.f;

        half8 r0 = *(const half8*)(xh + (size_t)s0 * HC + c0);
        half8 r1 = *(const half8*)(xh + (size_t)s1 * HC + c0);
        half8 r2 = *(const half8*)(xh + (size_t)s2 * HC + c0);
        half8 r3 = *(const half8*)(xh + (size_t)s3 * HC + c0);

#pragma unroll
        for (int k = 0; k < 8; ++k)
            acc[k] += e0 * (float)r0[k] + e1 * (float)r1[k]
                    + e2 * (float)r2[k] + e3 * (float)r3[k];
        den += e0 + e1 + e2 + e3;
    }

    // combine the two half-waves (same node, disjoint edge subsets)
    den += __shfl_xor(den, 32, 64);
#pragma unroll
    for (int k = 0; k < 8; ++k) acc[k] += __shfl_xor(acc[k], 32, 64);

    if (hl != 0) return;               // half 0 holds full sums; writes row
    const float inv = 1.f / (den + 1e-16f);

    float bgv[8], gv[8], bev[8];
    *(float4*)(bgv)     = *(const float4*)(bg + c0);
    *(float4*)(bgv + 4) = *(const float4*)(bg + c0 + 4);
    *(float4*)(gv)      = *(const float4*)(g + c0);
    *(float4*)(gv + 4)  = *(const float4*)(g + c0 + 4);
    *(float4*)(bev)     = *(const float4*)(be + c0);
    *(float4*)(bev + 4) = *(const float4*)(be + c0 + 4);

    half8* hp = (half8*)(h + (size_t)n * HC + c0);
    float r[8];
#pragma unroll
    for (int k = 0; k < 8; ++k)
        r[k] = fmaxf((acc[k] * inv + bgv[k]) * (gv[k] * BN_SCALE) + bev[k], 0.f);
    if (residual) {
        half8 old = *hp;
#pragma unroll
        for (int k = 0; k < 8; ++k) r[k] += (float)old[k];
    }
    half8 o;
#pragma unroll
    for (int k = 0; k < 8; ++k) o[k] = (_Float16)r[k];
    __builtin_nontemporal_store(o, hp);   // don't let h-stream evict xh
}

// ---------------------------------------------------------------------------
// Final fused edge MLP:
// Phase 1: per block, 64 edges; MFMA computes z_pre = ea@W1e + b1 into LDS.
// Phase 2: 4 threads/edge gather hs[src], hd[dst], ReLU, dot(W2), reduce.
// ---------------------------------------------------------------------------
__global__ __launch_bounds__(256) void edge_final(const float* __restrict__ ea,
                                                  const __half* __restrict__ w1et,
                                                  const float* __restrict__ b1,
                                                  const int* __restrict__ src,
                                                  const int* __restrict__ dst,
                                                  const __half* __restrict__ hshd,
                                                  const float* __restrict__ W2,
                                                  const float* __restrict__ b2,
                                                  float* __restrict__ out) {
    __shared__ float zl[64][36];   // stride 36: 16B-aligned rows, <=2-way banks
    const int wave = threadIdx.x >> 6, lane = threadIdx.x & 63;
    const int e0 = blockIdx.x * 64;
    const int lrow = lane & 15, kofs = (lane >> 4) * 8;

    // ---- Phase 1: MFMA z = ea @ W1e (K=32), 16 edges per wave ----
    int er = e0 + wave * 16 + lrow;
    if (er >= EE) er = EE - 1;
    const float* ap = ea + (size_t)er * F_EDGE + kofs;
    float4 f0 = *(const float4*)ap;
    float4 f1 = *(const float4*)(ap + 4);
    half8 a;
    a[0] = (_Float16)f0.x; a[1] = (_Float16)f0.y;
    a[2] = (_Float16)f0.z; a[3] = (_Float16)f0.w;
    a[4] = (_Float16)f1.x; a[5] = (_Float16)f1.y;
    a[6] = (_Float16)f1.z; a[7] = (_Float16)f1.w;

    half8 b0 = *(const half8*)(w1et + (size_t)lrow * 32 + kofs);
    half8 b1v = *(const half8*)(w1et + (size_t)(16 + lrow) * 32 + kofs);
    f32x4 acc0 = {}, acc1 = {};
    acc0 = __builtin_amdgcn_mfma_f32_16x16x32_f16(a, b0,  acc0, 0, 0, 0);
    acc1 = __builtin_amdgcn_mfma_f32_16x16x32_f16(a, b1v, acc1, 0, 0, 0);

    const int crow = (lane >> 4) * 4;
    const float bc0 = b1[lrow], bc1 = b1[16 + lrow];
#pragma unroll
    for (int r = 0; r < 4; ++r) {
        zl[wave * 16 + crow + r][lrow]      = acc0[r] + bc0;
        zl[wave * 16 + crow + r][16 + lrow] = acc1[r] + bc1;
    }
    __syncthreads();

    // ---- Phase 2: gather + ReLU + dot(W2) ----
    const int el = threadIdx.x >> 2, j0 = (threadIdx.x & 3) * 8;
    const int e = e0 + el;
    const bool ok = e < EE;
    const int s = ok ? src[e] : 0;
    const int d = ok ? dst[e] : 0;

    half8 hs = *(const half8*)(hshd + (size_t)s * 64 + j0);
    half8 hdv = *(const half8*)(hshd + (size_t)d * 64 + 32 + j0);
    float w2v[8];
    *(float4*)(w2v)     = *(const float4*)(W2 + j0);
    *(float4*)(w2v + 4) = *(const float4*)(W2 + j0 + 4);
    float4 z0 = *(const float4*)&zl[el][j0];
    float4 z1 = *(const float4*)&zl[el][j0 + 4];

    float acc = 0.f;
    const float* zp0 = &z0.x;
    const float* zp1 = &z1.x;
#pragma unroll
    for (int i = 0; i < 4; ++i) {
        float z = zp0[i] + (float)hs[i] + (float)hdv[i];
        acc += fmaxf(z, 0.f) * w2v[i];
    }
#pragma unroll
    for (int i = 0; i < 4; ++i) {
        float z = zp1[i] + (float)hs[4 + i] + (float)hdv[4 + i];
        acc += fmaxf(z, 0.f) * w2v[4 + i];
    }
    acc += __shfl_xor(acc, 1, 64);
    acc += __shfl_xor(acc, 2, 64);
    if (ok && (threadIdx.x & 3) == 0) out[e] = acc + b2[0];
}

// ---------------------------------------------------------------------------
extern "C" void kernel_launch(void* const* d_in, const int* in_sizes, int n_in,
                              void* d_out, int out_size, void* d_ws, size_t ws_size,
                              hipStream_t stream) {
    const float* x  = (const float*)d_in[0];
    const int*   ei = (const int*)d_in[1];
    const float* ea = (const float*)d_in[2];
    const float* Wp = (const float*)d_in[3];
    const float* bp = (const float*)d_in[4];
    const float* W1 = (const float*)d_in[23];
    const float* b1 = (const float*)d_in[24];
    const float* W2 = (const float*)d_in[25];
    const float* b2 = (const float*)d_in[26];
    const int* src = ei;
    const int* dst = ei + EE;

    // Workspace layout (float offsets). Matrix buffers padded to MPAD rows.
    float* ws = (float*)d_ws;
    __half* h      = (__half*)(ws);               // MPAD*256 halfs
    __half* xh     = (__half*)(ws + 12820000);    // MPAD*256 halfs
    __half* h0     = (__half*)(ws + 32050000);    // MPAD*64 halfs
    __half* hshd   = (__half*)(ws + 35260000);    // MPAD*64 halfs
    float*  a_s    = ws + 38470000;               // MPAD*4
    float*  a_d    = ws + 38880000;               // MPAD*4
    int*    rowptr = (int*)(ws + 41270000);       // NN+1
    int*    deg    = (int*)(ws + 41380000);       // NN
    int*    pos    = (int*)(ws + 41480000);       // EE
    int*    srcs   = (int*)(ws + 42490000);       // EE
    int*    bsum   = (int*)(ws + 42990000);       // NB_SCAN
    int*    boff   = (int*)(ws + 42991000);       // NB_SCAN
    __half* wpt    = (__half*)(ws + 42992000);    // 64x128
    __half* wg0t   = (__half*)(ws + 43000000);    // 256x64
    __half* wg1t   = (__half*)(ws + 43010000);    // 256x256
    __half* wg2t   = (__half*)(ws + 43045000);    // 256x256
    __half* w1t    = (__half*)(ws + 43080000);    // 64x256
    __half* w1et   = (__half*)(ws + 43090000);    // 32x32
    float*  out    = (float*)d_out;

    const int MB = MPAD / 128;   // 782 row-blocks

    // ---- prep (all weight transposes, one launch) + CSR build ----
    hipMemsetAsync(deg, 0, (size_t)NN * sizeof(int), stream);
    prep_all<<<(PREP_TOTAL + 255) / 256, 256, 0, stream>>>(
        Wp, (const float*)d_in[5], (const float*)d_in[11], (const float*)d_in[17],
        W1, wpt, wg0t, wg1t, wg2t, w1t, w1et);
    csr_count<<<(EE + 255) / 256, 256, 0, stream>>>(dst, deg, pos);
    scan1<<<NB_SCAN, 256, 0, stream>>>(deg, rowptr, bsum);
    scan2<<<1, 512, 0, stream>>>(bsum, boff);
    scan3<<<NB_SCAN, 256, 0, stream>>>(rowptr, boff);
    csr_scatter<<<(EE + 255) / 256, 256, 0, stream>>>(src, dst, rowptr, pos, srcs);

    // h0 = relu(x @ Wp + bp)  -- A read directly as fp32, cvt during staging
    mgemm2<F_NODE, 64, 1, 0, 1><<<dim3(MB, 1), 256, 0, stream>>>(
        nullptr, wpt, bp, h0, nullptr, nullptr, nullptr, nullptr, x);

    const __half* wgt_l[3] = {wg0t, wg1t, wg2t};
    for (int l = 0; l < 3; ++l) {
        const float* as_ = (const float*)d_in[6 + 6 * l];
        const float* ad_ = (const float*)d_in[7 + 6 * l];
        const float* bg  = (const float*)d_in[8 + 6 * l];
        const float* g   = (const float*)d_in[9 + 6 * l];
        const float* be  = (const float*)d_in[10 + 6 * l];

        if (l == 0) {
            mgemm2<CC, HC, 0, 1, 0><<<dim3(MB, 2), 256, 0, stream>>>(
                h0, wgt_l[0], nullptr, xh, as_, ad_, a_s, a_d, nullptr);
        } else {
            mgemm2<HC, HC, 0, 1, 0><<<dim3(MB, 2), 256, 0, stream>>>(
                h, wgt_l[l], nullptr, xh, as_, ad_, a_s, a_d, nullptr);
        }

        gather_agg<<<NN / 4, 256, 0, stream>>>(rowptr, srcs, a_s, a_d, xh,
                                               bg, g, be, h, l > 0 ? 1 : 0);
    }

    // hs|hd = h @ [W1s | W1d]
    mgemm2<HC, 64, 0, 0, 0><<<dim3(MB, 1), 256, 0, stream>>>(
        h, w1t, nullptr, hshd, nullptr, nullptr, nullptr, nullptr, nullptr);

    edge_final<<<(EE + 63) / 64, 256, 0, stream>>>(ea, w1et, b1, src, dst,
                                                   hshd, W2, b2, out);
}